// Round 2
// baseline (224.605 us; speedup 1.0000x reference)
//
#include <hip/hip_runtime.h>
#include <stdint.h>

typedef _Float16 f16;
typedef __attribute__((ext_vector_type(8))) _Float16 f16x8;
typedef __attribute__((ext_vector_type(4))) float f32x4;
typedef __attribute__((ext_vector_type(2))) unsigned int u32x2;
typedef __attribute__((ext_vector_type(4))) unsigned int u32x4;
typedef decltype(__builtin_amdgcn_cvt_pkrtz(0.f, 0.f)) h2_t;

#define S_LEN 2048
#define BATCH 8
#define D_IN  1024
#define DHALF 512

// low 32 bits of a generic pointer into LDS == LDS byte offset on gfx9xx
__device__ __forceinline__ unsigned lds_off(const void* p) {
  return (unsigned)(size_t)p;
}

// ---------------------------------------------------------------------------
// Projection: out[s,b,e] = sum_d X[s,b,d] * W[e,d] + bias[e], stored fp16.
// GEMM view: A (M=16384, K=1024) row-major; B = W (N=512, K=1024) row-major.
// Tile 128x128x32, 4 waves, 64x64 per wave.
// 2-phase pipeline: global f32 loads (t+1) -> regs issued BEFORE MFMA(t);
// cvt_pkrtz + LDS write after MFMA; single draining barrier per K-step.
// LDS fp16 stride 40 (80B rows -> conflict-light b128 frag reads).
// ---------------------------------------------------------------------------
__global__ __launch_bounds__(256, 3) void proj_kernel(
    const float* __restrict__ Xq, const float* __restrict__ Xk, const float* __restrict__ Xv,
    const float* __restrict__ Wq, const float* __restrict__ Wk, const float* __restrict__ Wv,
    const float* __restrict__ bq, const float* __restrict__ bk, const float* __restrict__ bv,
    f16* __restrict__ oq, f16* __restrict__ ok, f16* __restrict__ ov)
{
  const int z = blockIdx.z;
  const float* X    = (z == 0) ? Xq : (z == 1) ? Xk : Xv;
  const float* W    = (z == 0) ? Wq : (z == 1) ? Wk : Wv;
  const float* bias = (z == 0) ? bq : (z == 1) ? bk : bv;
  f16* out          = (z == 0) ? oq : (z == 1) ? ok : ov;

  const int m0 = blockIdx.x * 128;
  const int n0 = blockIdx.y * 128;
  const int tid = threadIdx.x;
  const int lane = tid & 63;
  const int wave = tid >> 6;
  const int wr = wave >> 1, wc = wave & 1;
  const int g = lane >> 4, rl = lane & 15;

  __shared__ f16 As[2][128 * 40];
  __shared__ f16 Bs[2][128 * 40];

  f32x4 acc[4][4];
#pragma unroll
  for (int i = 0; i < 4; i++)
#pragma unroll
    for (int j = 0; j < 4; j++) acc[i][j] = (f32x4){0.f, 0.f, 0.f, 0.f};

  const int srow = tid >> 1;            // 0..127
  const int sh   = (tid & 1) * 16;      // 0 / 16

  const float* gA = X + (size_t)(m0 + srow) * D_IN + sh;
  const float* gB = W + (size_t)(n0 + srow) * D_IN + sh;

  f32x4 ra0, ra1, ra2, ra3, rb0, rb1, rb2, rb3;

#define PLOAD(K0)                                                        \
  ra0 = *(const f32x4*)(gA + (K0));      ra1 = *(const f32x4*)(gA + (K0) + 4);  \
  ra2 = *(const f32x4*)(gA + (K0) + 8);  ra3 = *(const f32x4*)(gA + (K0) + 12); \
  rb0 = *(const f32x4*)(gB + (K0));      rb1 = *(const f32x4*)(gB + (K0) + 4);  \
  rb2 = *(const f32x4*)(gB + (K0) + 8);  rb3 = *(const f32x4*)(gB + (K0) + 12);

#define PWRITE(BUF) {                                                    \
  union H8 { h2_t h2[4]; f16x8 v; };                                     \
  H8 pa0, pa1, pb0, pb1;                                                 \
  pa0.h2[0] = __builtin_amdgcn_cvt_pkrtz(ra0.x, ra0.y);                  \
  pa0.h2[1] = __builtin_amdgcn_cvt_pkrtz(ra0.z, ra0.w);                  \
  pa0.h2[2] = __builtin_amdgcn_cvt_pkrtz(ra1.x, ra1.y);                  \
  pa0.h2[3] = __builtin_amdgcn_cvt_pkrtz(ra1.z, ra1.w);                  \
  pa1.h2[0] = __builtin_amdgcn_cvt_pkrtz(ra2.x, ra2.y);                  \
  pa1.h2[1] = __builtin_amdgcn_cvt_pkrtz(ra2.z, ra2.w);                  \
  pa1.h2[2] = __builtin_amdgcn_cvt_pkrtz(ra3.x, ra3.y);                  \
  pa1.h2[3] = __builtin_amdgcn_cvt_pkrtz(ra3.z, ra3.w);                  \
  pb0.h2[0] = __builtin_amdgcn_cvt_pkrtz(rb0.x, rb0.y);                  \
  pb0.h2[1] = __builtin_amdgcn_cvt_pkrtz(rb0.z, rb0.w);                  \
  pb0.h2[2] = __builtin_amdgcn_cvt_pkrtz(rb1.x, rb1.y);                  \
  pb0.h2[3] = __builtin_amdgcn_cvt_pkrtz(rb1.z, rb1.w);                  \
  pb1.h2[0] = __builtin_amdgcn_cvt_pkrtz(rb2.x, rb2.y);                  \
  pb1.h2[1] = __builtin_amdgcn_cvt_pkrtz(rb2.z, rb2.w);                  \
  pb1.h2[2] = __builtin_amdgcn_cvt_pkrtz(rb3.x, rb3.y);                  \
  pb1.h2[3] = __builtin_amdgcn_cvt_pkrtz(rb3.z, rb3.w);                  \
  *(f16x8*)&As[BUF][srow * 40 + sh]     = pa0.v;                         \
  *(f16x8*)&As[BUF][srow * 40 + sh + 8] = pa1.v;                         \
  *(f16x8*)&Bs[BUF][srow * 40 + sh]     = pb0.v;                         \
  *(f16x8*)&Bs[BUF][srow * 40 + sh + 8] = pb1.v; }

  PLOAD(0);
  PWRITE(0);
  __syncthreads();

  int cur = 0;
#pragma unroll 2
  for (int k0 = 0; k0 < D_IN; k0 += 32) {
    const bool more = (k0 + 32 < D_IN);
    if (more) { PLOAD(k0 + 32); }

    f16x8 af[4], bf[4];
#pragma unroll
    for (int i = 0; i < 4; i++)
      af[i] = *(const f16x8*)&As[cur][(wr * 64 + i * 16 + rl) * 40 + g * 8];
#pragma unroll
    for (int j = 0; j < 4; j++)
      bf[j] = *(const f16x8*)&Bs[cur][(wc * 64 + j * 16 + rl) * 40 + g * 8];
#pragma unroll
    for (int i = 0; i < 4; i++)
#pragma unroll
      for (int j = 0; j < 4; j++)
        acc[i][j] = __builtin_amdgcn_mfma_f32_16x16x32_f16(af[i], bf[j], acc[i][j], 0, 0, 0);

    if (more) {
      PWRITE(cur ^ 1);
      __syncthreads();   // compiler drains lgkmcnt before s_barrier -> safe 1-barrier rotation
      cur ^= 1;
    }
  }
#undef PLOAD
#undef PWRITE

  // epilogue: + bias, cast fp16 (RTN), C/D layout: col = lane&15, row = (lane>>4)*4 + r
#pragma unroll
  for (int i = 0; i < 4; i++) {
    const int row = m0 + wr * 64 + i * 16 + g * 4;
#pragma unroll
    for (int j = 0; j < 4; j++) {
      const int col = n0 + wc * 64 + j * 16 + rl;
      const float bb = bias[col];
#pragma unroll
      for (int r = 0; r < 4; r++)
        out[(size_t)(row + r) * DHALF + col] = (f16)(acc[i][j][r] + bb);
    }
  }
}

// ---------------------------------------------------------------------------
// Batched GEMM-TN: C[b] = A[b] (M x K, K-contig) * B[b] (K x N, N-contig).
// B is transpose-staged into [4k][16n] subtiles; phys block order
// {0,2,4,6,1,3,5,7} so ds_read_b64_tr_b16 (+offset:512) delivers the
// fp16 B-fragment (lane holds B[k=8g+j][n=l&15], j=0..7).
// Same 2-phase pipeline as proj_kernel.
// EPI=0: apply attn mask, store f32 logits.  EPI=1: store f32 to out.
// ---------------------------------------------------------------------------
template <int EPI>
__global__ __launch_bounds__(256, 3) void gemm_tn_kernel(
    const f16* __restrict__ A, long batchA, int lda,
    const f16* __restrict__ Bm, long batchB, int ldb,
    int Ksize,
    const int* __restrict__ mask,
    float* __restrict__ out, long batchOut, int ldo)
{
  const int bz = blockIdx.z;
  const int n0 = blockIdx.x * 128;
  const int m0 = blockIdx.y * 128;
  const f16* Ab = A + (size_t)bz * batchA;
  const f16* Bb = Bm + (size_t)bz * batchB;

  const int tid = threadIdx.x, lane = tid & 63, wave = tid >> 6;
  const int wr = wave >> 1, wc = wave & 1;
  const int g = lane >> 4, rl = lane & 15;

  __shared__ f16 As[2][128 * 40];   // padded stride 40
  __shared__ f16 Bs[2][32 * 128];   // [e_blk(8)][phys(8)] blocks of [4][16] fp16

  f32x4 acc[4][4];
#pragma unroll
  for (int i = 0; i < 4; i++)
#pragma unroll
    for (int j = 0; j < 4; j++) acc[i][j] = (f32x4){0.f, 0.f, 0.f, 0.f};

  const int arow = tid >> 1;
  const int ah   = (tid & 1) * 16;
  const int brow = tid >> 3;            // k-row 0..31
  const int bcol = (tid & 7) * 16;      // n offset 0..112
  const int sblk = brow >> 2;
  const int phys = ((sblk & 1) << 2) | (sblk >> 1);
  const int bwoff = ((tid & 7) * 8 + phys) * 128 + (brow & 3) * 32;  // bytes in Bs buf
  const f16* gA = Ab + (size_t)(m0 + arow) * lda + ah;
  const f16* gB = Bb + (size_t)brow * ldb + n0 + bcol;

  const unsigned bs_base = lds_off(&Bs[0][0]);

  f16x8 va0, va1, vb0, vb1;

#define GLOAD(K0)                                                       \
  va0 = *(const f16x8*)(gA + (K0));                                     \
  va1 = *(const f16x8*)(gA + (K0) + 8);                                 \
  { const f16* gb = gB + (size_t)(K0) * ldb;                            \
    vb0 = *(const f16x8*)(gb);                                          \
    vb1 = *(const f16x8*)(gb + 8); }

#define GWRITE(BUF) {                                                   \
  *(f16x8*)&As[BUF][arow * 40 + ah]     = va0;                          \
  *(f16x8*)&As[BUF][arow * 40 + ah + 8] = va1;                          \
  char* wb = (char*)&Bs[BUF][0] + bwoff;                                \
  *(f16x8*)wb        = vb0;                                             \
  *(f16x8*)(wb + 16) = vb1; }

  GLOAD(0);
  GWRITE(0);
  __syncthreads();

  int cur = 0;
#pragma unroll 2
  for (int k0 = 0; k0 < Ksize; k0 += 32) {
    const bool more = (k0 + 32 < Ksize);
    if (more) { GLOAD(k0 + 32); }

    f16x8 af[4];
#pragma unroll
    for (int i = 0; i < 4; i++)
      af[i] = *(const f16x8*)&As[cur][(wr * 64 + i * 16 + rl) * 40 + g * 8];

    f16x8 bf[4];
#pragma unroll
    for (int j = 0; j < 4; j++) {
      unsigned addr = bs_base + (unsigned)cur * 8192u +
                      (unsigned)((wc * 4 + j) * 1024) + (unsigned)lane * 8u;
      u32x2 lo, hi;
      asm volatile("ds_read_b64_tr_b16 %0, %1" : "=v"(lo) : "v"(addr));
      asm volatile("ds_read_b64_tr_b16 %0, %1 offset:512" : "=v"(hi) : "v"(addr));
      union { u32x4 u; f16x8 h; } cc;
      cc.u = (u32x4){lo.x, lo.y, hi.x, hi.y};
      bf[j] = cc.h;
    }
    // rule 18: fence tr-read results before register-only MFMA consumers
    asm volatile("s_waitcnt lgkmcnt(0)" ::: "memory");
    __builtin_amdgcn_sched_barrier(0);

#pragma unroll
    for (int i = 0; i < 4; i++)
#pragma unroll
      for (int j = 0; j < 4; j++)
        acc[i][j] = __builtin_amdgcn_mfma_f32_16x16x32_f16(af[i], bf[j], acc[i][j], 0, 0, 0);

    if (more) {
      GWRITE(cur ^ 1);
      __syncthreads();   // single draining barrier per K-step
      cur ^= 1;
    }
  }
#undef GLOAD
#undef GWRITE

  float* ob = out + (size_t)bz * batchOut;
#pragma unroll
  for (int i = 0; i < 4; i++) {
    const int row = m0 + wr * 64 + i * 16 + g * 4;
#pragma unroll
    for (int j = 0; j < 4; j++) {
      const int col = n0 + wc * 64 + j * 16 + rl;
#pragma unroll
      for (int r = 0; r < 4; r++) {
        float val = acc[i][j][r];
        if (EPI == 0) {
          if (mask[(row + r) * DHALF + col] != 0) val = -1e30f;
        }
        ob[(size_t)(row + r) * ldo + col] = val;
      }
    }
  }
}

// ---------------------------------------------------------------------------
// Row softmax over e (512) for 4096 rows; one wave per row; fp16 output.
// ---------------------------------------------------------------------------
__global__ __launch_bounds__(256) void softmax_kernel(
    const float* __restrict__ logits, f16* __restrict__ P)
{
  const int row  = blockIdx.x * 4 + (threadIdx.x >> 6);
  const int lane = threadIdx.x & 63;
  const float* rp = logits + (size_t)row * DHALF + lane * 8;
  f32x4 x0 = *(const f32x4*)rp;
  f32x4 x1 = *(const f32x4*)(rp + 4);

  float m = fmaxf(fmaxf(fmaxf(x0.x, x0.y), fmaxf(x0.z, x0.w)),
                  fmaxf(fmaxf(x1.x, x1.y), fmaxf(x1.z, x1.w)));
#pragma unroll
  for (int off = 32; off > 0; off >>= 1) m = fmaxf(m, __shfl_xor(m, off, 64));

  float e0 = __expf(x0.x - m), e1 = __expf(x0.y - m);
  float e2 = __expf(x0.z - m), e3 = __expf(x0.w - m);
  float e4 = __expf(x1.x - m), e5 = __expf(x1.y - m);
  float e6 = __expf(x1.z - m), e7 = __expf(x1.w - m);
  float s = ((e0 + e1) + (e2 + e3)) + ((e4 + e5) + (e6 + e7));
#pragma unroll
  for (int off = 32; off > 0; off >>= 1) s += __shfl_xor(s, off, 64);
  const float inv = 1.0f / s;

  union { h2_t h2[4]; f16x8 v; } o;
  o.h2[0] = __builtin_amdgcn_cvt_pkrtz(e0 * inv, e1 * inv);
  o.h2[1] = __builtin_amdgcn_cvt_pkrtz(e2 * inv, e3 * inv);
  o.h2[2] = __builtin_amdgcn_cvt_pkrtz(e4 * inv, e5 * inv);
  o.h2[3] = __builtin_amdgcn_cvt_pkrtz(e6 * inv, e7 * inv);
  *(f16x8*)(P + (size_t)row * DHALF + lane * 8) = o.v;
}

// ---------------------------------------------------------------------------
extern "C" void kernel_launch(void* const* d_in, const int* in_sizes, int n_in,
                              void* d_out, int out_size, void* d_ws, size_t ws_size,
                              hipStream_t stream) {
  const float* q    = (const float*)d_in[0];
  const float* k    = (const float*)d_in[1];
  const float* v    = (const float*)d_in[2];
  const int*   mask = (const int*)d_in[3];
  const float* Wq   = (const float*)d_in[4];
  const float* bq   = (const float*)d_in[5];
  const float* Wk   = (const float*)d_in[6];
  const float* bk   = (const float*)d_in[7];
  const float* Wv   = (const float*)d_in[8];
  const float* bv   = (const float*)d_in[9];

  char* ws = (char*)d_ws;
  f16*   qt     = (f16*)(ws);                                  // 16 MB
  f16*   kt     = (f16*)(ws + 16777216);                       // 16 MB
  f16*   vt     = (f16*)(ws + 2 * 16777216);                   // 16 MB
  float* logits = (float*)(ws + 3 * 16777216);                 // 8 MB
  f16*   P      = (f16*)(ws + 3 * 16777216 + 8388608);         // 4 MB

  // 1) fused q/k/v projections -> fp16 (S,B,DH) flat
  proj_kernel<<<dim3(128, 4, 3), 256, 0, stream>>>(q, k, v, Wq, Wk, Wv, bq, bk, bv,
                                                   qt, kt, vt);
  // 2) logits[b,d,e] = sum_s q_[b,d,s] k_[b,s,e]  (+mask -> -1e30)
  gemm_tn_kernel<0><<<dim3(4, 4, 8), 256, 0, stream>>>(
      qt, 1048576L, 2048, kt, 1048576L, 512, 2048, mask, logits, 262144L, 512);
  // 3) P = softmax(logits) over e, fp16
  softmax_kernel<<<dim3(1024), 256, 0, stream>>>(logits, P);
  // 4) out[b,d,s] = sum_e P[b,d,e] v_[b,e,s]  -> f32 d_out
  gemm_tn_kernel<1><<<dim3(16, 4, 8), 256, 0, stream>>>(
      P, 262144L, 512, vt, 1048576L, 2048, 512, nullptr, (float*)d_out, 1048576L, 2048);
}

// Round 3
// 206.813 us; speedup vs baseline: 1.0860x; 1.0860x over previous
//
#include <hip/hip_runtime.h>
#include <stdint.h>

typedef _Float16 f16;
typedef __attribute__((ext_vector_type(8))) _Float16 f16x8;
typedef __attribute__((ext_vector_type(4))) float f32x4;
typedef __attribute__((ext_vector_type(2))) unsigned int u32x2;
typedef __attribute__((ext_vector_type(4))) unsigned int u32x4;
typedef decltype(__builtin_amdgcn_cvt_pkrtz(0.f, 0.f)) h2_t;

#define S_LEN 2048
#define BATCH 8
#define D_IN  1024
#define DHALF 512

__device__ __forceinline__ unsigned lds_off(const void* p) {
  return (unsigned)(size_t)p;
}

// ---------------------------------------------------------------------------
// Projection: out[s,b,e] = sum_d X[s,b,d] * W[e,d] + bias[e], stored fp16.
// Tile 128x128x32, 4 waves. DEPTH-2 register pipeline:
//   issue loads(t+2) -> COMPUTE(t) -> write(t+1 regs -> LDS) -> barrier
// Two static register sets (rule 20), two LDS buffers, one barrier/K-step.
// The ds_write's implicit vmcnt(8) is covered by a full K-step of compute.
// ---------------------------------------------------------------------------
__global__ __launch_bounds__(256, 2) void proj_kernel(
    const float* __restrict__ Xq, const float* __restrict__ Xk, const float* __restrict__ Xv,
    const float* __restrict__ Wq, const float* __restrict__ Wk, const float* __restrict__ Wv,
    const float* __restrict__ bq, const float* __restrict__ bk, const float* __restrict__ bv,
    f16* __restrict__ oq, f16* __restrict__ ok, f16* __restrict__ ov)
{
  const int z = blockIdx.z;
  const float* X    = (z == 0) ? Xq : (z == 1) ? Xk : Xv;
  const float* W    = (z == 0) ? Wq : (z == 1) ? Wk : Wv;
  const float* bias = (z == 0) ? bq : (z == 1) ? bk : bv;
  f16* out          = (z == 0) ? oq : (z == 1) ? ok : ov;

  const int m0 = blockIdx.x * 128;
  const int n0 = blockIdx.y * 128;
  const int tid = threadIdx.x;
  const int lane = tid & 63;
  const int wave = tid >> 6;
  const int wr = wave >> 1, wc = wave & 1;
  const int g = lane >> 4, rl = lane & 15;

  __shared__ f16 As[2][128 * 40];
  __shared__ f16 Bs[2][128 * 40];

  f32x4 acc[4][4];
#pragma unroll
  for (int i = 0; i < 4; i++)
#pragma unroll
    for (int j = 0; j < 4; j++) acc[i][j] = (f32x4){0.f, 0.f, 0.f, 0.f};

  const int srow = tid >> 1;            // 0..127
  const int sh   = (tid & 1) * 16;      // 0 / 16

  const float* gA = X + (size_t)(m0 + srow) * D_IN + sh;
  const float* gB = W + (size_t)(n0 + srow) * D_IN + sh;

  // two static staging sets, 8 f32x4 each
  f32x4 a0_0, a0_1, a0_2, a0_3, b0_0, b0_1, b0_2, b0_3;   // set 0
  f32x4 a1_0, a1_1, a1_2, a1_3, b1_0, b1_1, b1_2, b1_3;   // set 1

#define PLOAD(S, K0)                                                          \
  a##S##_0 = *(const f32x4*)(gA + (K0));      a##S##_1 = *(const f32x4*)(gA + (K0) + 4);  \
  a##S##_2 = *(const f32x4*)(gA + (K0) + 8);  a##S##_3 = *(const f32x4*)(gA + (K0) + 12); \
  b##S##_0 = *(const f32x4*)(gB + (K0));      b##S##_1 = *(const f32x4*)(gB + (K0) + 4);  \
  b##S##_2 = *(const f32x4*)(gB + (K0) + 8);  b##S##_3 = *(const f32x4*)(gB + (K0) + 12);

#define PWRITE(S, BUF) {                                                      \
  union H8 { h2_t h2[4]; f16x8 v; };                                          \
  H8 pa0, pa1, pb0, pb1;                                                      \
  pa0.h2[0] = __builtin_amdgcn_cvt_pkrtz(a##S##_0.x, a##S##_0.y);             \
  pa0.h2[1] = __builtin_amdgcn_cvt_pkrtz(a##S##_0.z, a##S##_0.w);             \
  pa0.h2[2] = __builtin_amdgcn_cvt_pkrtz(a##S##_1.x, a##S##_1.y);             \
  pa0.h2[3] = __builtin_amdgcn_cvt_pkrtz(a##S##_1.z, a##S##_1.w);             \
  pa1.h2[0] = __builtin_amdgcn_cvt_pkrtz(a##S##_2.x, a##S##_2.y);             \
  pa1.h2[1] = __builtin_amdgcn_cvt_pkrtz(a##S##_2.z, a##S##_2.w);             \
  pa1.h2[2] = __builtin_amdgcn_cvt_pkrtz(a##S##_3.x, a##S##_3.y);             \
  pa1.h2[3] = __builtin_amdgcn_cvt_pkrtz(a##S##_3.z, a##S##_3.w);             \
  pb0.h2[0] = __builtin_amdgcn_cvt_pkrtz(b##S##_0.x, b##S##_0.y);             \
  pb0.h2[1] = __builtin_amdgcn_cvt_pkrtz(b##S##_0.z, b##S##_0.w);             \
  pb0.h2[2] = __builtin_amdgcn_cvt_pkrtz(b##S##_1.x, b##S##_1.y);             \
  pb0.h2[3] = __builtin_amdgcn_cvt_pkrtz(b##S##_1.z, b##S##_1.w);             \
  pb1.h2[0] = __builtin_amdgcn_cvt_pkrtz(b##S##_2.x, b##S##_2.y);             \
  pb1.h2[1] = __builtin_amdgcn_cvt_pkrtz(b##S##_2.z, b##S##_2.w);             \
  pb1.h2[2] = __builtin_amdgcn_cvt_pkrtz(b##S##_3.x, b##S##_3.y);             \
  pb1.h2[3] = __builtin_amdgcn_cvt_pkrtz(b##S##_3.z, b##S##_3.w);             \
  *(f16x8*)&As[BUF][srow * 40 + sh]     = pa0.v;                              \
  *(f16x8*)&As[BUF][srow * 40 + sh + 8] = pa1.v;                              \
  *(f16x8*)&Bs[BUF][srow * 40 + sh]     = pb0.v;                              \
  *(f16x8*)&Bs[BUF][srow * 40 + sh + 8] = pb1.v; }

#define PCOMPUTE(BUF) {                                                       \
  f16x8 af[4], bf[4];                                                         \
  _Pragma("unroll")                                                           \
  for (int i = 0; i < 4; i++)                                                 \
    af[i] = *(const f16x8*)&As[BUF][(wr * 64 + i * 16 + rl) * 40 + g * 8];    \
  _Pragma("unroll")                                                           \
  for (int j = 0; j < 4; j++)                                                 \
    bf[j] = *(const f16x8*)&Bs[BUF][(wc * 64 + j * 16 + rl) * 40 + g * 8];    \
  _Pragma("unroll")                                                           \
  for (int i = 0; i < 4; i++)                                                 \
    _Pragma("unroll")                                                         \
    for (int j = 0; j < 4; j++)                                               \
      acc[i][j] = __builtin_amdgcn_mfma_f32_16x16x32_f16(af[i], bf[j], acc[i][j], 0, 0, 0); }

  // prologue: steps 0,1 in flight; step 0 staged to buf0
  PLOAD(0, 0);
  PLOAD(1, 32);
  PWRITE(0, 0);
  __syncthreads();

  // 32 K-steps, two per iteration (even->buf0, odd->buf1)
  for (int it = 0; it < 16; ++it) {
    const int s = it * 2;
    if (s + 2 < 32) { PLOAD(0, (s + 2) * 32); }   // prefetch step s+2 into set0
    PCOMPUTE(0);                                   // compute step s from buf0
    PWRITE(1, 1);                                  // stage step s+1 (set1, loaded 1 iter ago)
    __syncthreads();
    if (s + 3 < 32) { PLOAD(1, (s + 3) * 32); }   // prefetch step s+3 into set1
    PCOMPUTE(1);                                   // compute step s+1 from buf1
    if (s + 2 < 32) {
      PWRITE(0, 0);                                // stage step s+2
      __syncthreads();
    }
  }
#undef PLOAD
#undef PWRITE
#undef PCOMPUTE

  // epilogue: + bias, cast fp16; C/D layout: col = lane&15, row = (lane>>4)*4 + r
#pragma unroll
  for (int i = 0; i < 4; i++) {
    const int row = m0 + wr * 64 + i * 16 + g * 4;
#pragma unroll
    for (int j = 0; j < 4; j++) {
      const int col = n0 + wc * 64 + j * 16 + rl;
      const float bb = bias[col];
#pragma unroll
      for (int r = 0; r < 4; r++)
        out[(size_t)(row + r) * DHALF + col] = (f16)(acc[i][j][r] + bb);
    }
  }
}

// ---------------------------------------------------------------------------
// Batched GEMM-TN: C[b] = A[b] (M x K, K-contig) * B[b] (K x N, N-contig).
// Template MI = M-fragments per wave (4 -> BM=128, 2 -> BM=64).
// B transpose-staged into [4k][16n] subtiles, phys order {0,2,4,6,1,3,5,7},
// read via ds_read_b64_tr_b16 (+offset:512).
// EPI=0: apply attn mask, store f32 logits.  EPI=1: store f32 to out.
// ---------------------------------------------------------------------------
template <int EPI, int MI>
__global__ __launch_bounds__(256, 3) void gemm_tn_kernel(
    const f16* __restrict__ A, long batchA, int lda,
    const f16* __restrict__ Bm, long batchB, int ldb,
    int Ksize,
    const int* __restrict__ mask,
    float* __restrict__ out, long batchOut, int ldo)
{
  constexpr int BM = MI * 32;            // block M-tile
  const int bz = blockIdx.z;
  const int n0 = blockIdx.x * 128;
  const int m0 = blockIdx.y * BM;
  const f16* Ab = A + (size_t)bz * batchA;
  const f16* Bb = Bm + (size_t)bz * batchB;

  const int tid = threadIdx.x, lane = tid & 63, wave = tid >> 6;
  const int wr = wave >> 1, wc = wave & 1;
  const int g = lane >> 4, rl = lane & 15;

  __shared__ f16 As[2][BM * 40];         // padded stride 40
  __shared__ f16 Bs[2][32 * 128];        // [n_blk(8)][phys(8)] blocks of [4][16]

  f32x4 acc[MI][4];
#pragma unroll
  for (int i = 0; i < MI; i++)
#pragma unroll
    for (int j = 0; j < 4; j++) acc[i][j] = (f32x4){0.f, 0.f, 0.f, 0.f};

  // A staging: BM*32 f16 by 256 threads
  const int arow = (MI == 4) ? (tid >> 1) : (tid >> 2);
  const int ah   = (MI == 4) ? ((tid & 1) * 16) : ((tid & 3) * 8);
  const int brow = tid >> 3;             // k-row 0..31
  const int bcol = (tid & 7) * 16;       // n offset
  const int sblk = brow >> 2;
  const int phys = ((sblk & 1) << 2) | (sblk >> 1);
  const int bwoff = ((tid & 7) * 8 + phys) * 128 + (brow & 3) * 32;  // bytes
  const f16* gA = Ab + (size_t)(m0 + arow) * lda + ah;
  const f16* gB = Bb + (size_t)brow * ldb + n0 + bcol;

  const unsigned bs_base = lds_off(&Bs[0][0]);

  f16x8 va0, va1, vb0, vb1;

#define GLOAD(K0)                                                       \
  va0 = *(const f16x8*)(gA + (K0));                                     \
  if (MI == 4) va1 = *(const f16x8*)(gA + (K0) + 8);                    \
  { const f16* gb = gB + (size_t)(K0) * ldb;                            \
    vb0 = *(const f16x8*)(gb);                                          \
    vb1 = *(const f16x8*)(gb + 8); }

#define GWRITE(BUF) {                                                   \
  *(f16x8*)&As[BUF][arow * 40 + ah] = va0;                              \
  if (MI == 4) *(f16x8*)&As[BUF][arow * 40 + ah + 8] = va1;             \
  char* wb = (char*)&Bs[BUF][0] + bwoff;                                \
  *(f16x8*)wb        = vb0;                                             \
  *(f16x8*)(wb + 16) = vb1; }

  GLOAD(0);
  GWRITE(0);
  __syncthreads();

  int cur = 0;
#pragma unroll 2
  for (int k0 = 0; k0 < Ksize; k0 += 32) {
    const bool more = (k0 + 32 < Ksize);
    if (more) { GLOAD(k0 + 32); }

    f16x8 af[MI];
#pragma unroll
    for (int i = 0; i < MI; i++)
      af[i] = *(const f16x8*)&As[cur][(wr * (MI * 16) + i * 16 + rl) * 40 + g * 8];

    f16x8 bf[4];
#pragma unroll
    for (int j = 0; j < 4; j++) {
      unsigned addr = bs_base + (unsigned)cur * 8192u +
                      (unsigned)((wc * 4 + j) * 1024) + (unsigned)lane * 8u;
      u32x2 lo, hi;
      asm volatile("ds_read_b64_tr_b16 %0, %1" : "=v"(lo) : "v"(addr));
      asm volatile("ds_read_b64_tr_b16 %0, %1 offset:512" : "=v"(hi) : "v"(addr));
      union { u32x4 u; f16x8 h; } cc;
      cc.u = (u32x4){lo.x, lo.y, hi.x, hi.y};
      bf[j] = cc.h;
    }
    // rule 18: fence tr-read results before register-only MFMA consumers
    asm volatile("s_waitcnt lgkmcnt(0)" ::: "memory");
    __builtin_amdgcn_sched_barrier(0);

#pragma unroll
    for (int i = 0; i < MI; i++)
#pragma unroll
      for (int j = 0; j < 4; j++)
        acc[i][j] = __builtin_amdgcn_mfma_f32_16x16x32_f16(af[i], bf[j], acc[i][j], 0, 0, 0);

    if (more) {
      GWRITE(cur ^ 1);
      __syncthreads();
      cur ^= 1;
    }
  }
#undef GLOAD
#undef GWRITE

  float* ob = out + (size_t)bz * batchOut;
#pragma unroll
  for (int i = 0; i < MI; i++) {
    const int row = m0 + wr * (MI * 16) + i * 16 + g * 4;
#pragma unroll
    for (int j = 0; j < 4; j++) {
      const int col = n0 + wc * 64 + j * 16 + rl;
#pragma unroll
      for (int r = 0; r < 4; r++) {
        float val = acc[i][j][r];
        if (EPI == 0) {
          if (mask[(row + r) * DHALF + col] != 0) val = -1e30f;
        }
        ob[(size_t)(row + r) * ldo + col] = val;
      }
    }
  }
}

// ---------------------------------------------------------------------------
// Row softmax over e (512) for 4096 rows; one wave per row; fp16 output.
// ---------------------------------------------------------------------------
__global__ __launch_bounds__(256) void softmax_kernel(
    const float* __restrict__ logits, f16* __restrict__ P)
{
  const int row  = blockIdx.x * 4 + (threadIdx.x >> 6);
  const int lane = threadIdx.x & 63;
  const float* rp = logits + (size_t)row * DHALF + lane * 8;
  f32x4 x0 = *(const f32x4*)rp;
  f32x4 x1 = *(const f32x4*)(rp + 4);

  float m = fmaxf(fmaxf(fmaxf(x0.x, x0.y), fmaxf(x0.z, x0.w)),
                  fmaxf(fmaxf(x1.x, x1.y), fmaxf(x1.z, x1.w)));
#pragma unroll
  for (int off = 32; off > 0; off >>= 1) m = fmaxf(m, __shfl_xor(m, off, 64));

  float e0 = __expf(x0.x - m), e1 = __expf(x0.y - m);
  float e2 = __expf(x0.z - m), e3 = __expf(x0.w - m);
  float e4 = __expf(x1.x - m), e5 = __expf(x1.y - m);
  float e6 = __expf(x1.z - m), e7 = __expf(x1.w - m);
  float s = ((e0 + e1) + (e2 + e3)) + ((e4 + e5) + (e6 + e7));
#pragma unroll
  for (int off = 32; off > 0; off >>= 1) s += __shfl_xor(s, off, 64);
  const float inv = 1.0f / s;

  union { h2_t h2[4]; f16x8 v; } o;
  o.h2[0] = __builtin_amdgcn_cvt_pkrtz(e0 * inv, e1 * inv);
  o.h2[1] = __builtin_amdgcn_cvt_pkrtz(e2 * inv, e3 * inv);
  o.h2[2] = __builtin_amdgcn_cvt_pkrtz(e4 * inv, e5 * inv);
  o.h2[3] = __builtin_amdgcn_cvt_pkrtz(e6 * inv, e7 * inv);
  *(f16x8*)(P + (size_t)row * DHALF + lane * 8) = o.v;
}

// ---------------------------------------------------------------------------
extern "C" void kernel_launch(void* const* d_in, const int* in_sizes, int n_in,
                              void* d_out, int out_size, void* d_ws, size_t ws_size,
                              hipStream_t stream) {
  const float* q    = (const float*)d_in[0];
  const float* k    = (const float*)d_in[1];
  const float* v    = (const float*)d_in[2];
  const int*   mask = (const int*)d_in[3];
  const float* Wq   = (const float*)d_in[4];
  const float* bq   = (const float*)d_in[5];
  const float* Wk   = (const float*)d_in[6];
  const float* bk   = (const float*)d_in[7];
  const float* Wv   = (const float*)d_in[8];
  const float* bv   = (const float*)d_in[9];

  char* ws = (char*)d_ws;
  f16*   qt     = (f16*)(ws);                                  // 16 MB
  f16*   kt     = (f16*)(ws + 16777216);                       // 16 MB
  f16*   vt     = (f16*)(ws + 2 * 16777216);                   // 16 MB
  float* logits = (float*)(ws + 3 * 16777216);                 // 8 MB
  f16*   P      = (f16*)(ws + 3 * 16777216 + 8388608);         // 4 MB

  // 1) fused q/k/v projections -> fp16 (S,B,DH) flat
  proj_kernel<<<dim3(128, 4, 3), 256, 0, stream>>>(q, k, v, Wq, Wk, Wv, bq, bk, bv,
                                                   qt, kt, vt);
  // 2) logits[b,d,e] = sum_s q_[b,d,s] k_[b,s,e]  (+mask -> -1e30), BM=64 -> 256 blocks
  gemm_tn_kernel<0, 2><<<dim3(4, 8, 8), 256, 0, stream>>>(
      qt, 1048576L, 2048, kt, 1048576L, 512, 2048, mask, logits, 262144L, 512);
  // 3) P = softmax(logits) over e, fp16
  softmax_kernel<<<dim3(1024), 256, 0, stream>>>(logits, P);
  // 4) out[b,d,s] = sum_e P[b,d,e] v_[b,e,s]  -> f32 d_out, BM=128 -> 512 blocks
  gemm_tn_kernel<1, 4><<<dim3(16, 4, 8), 256, 0, stream>>>(
      P, 262144L, 512, vt, 1048576L, 2048, 512, nullptr, (float*)d_out, 1048576L, 2048);
}

// Round 4
// 184.917 us; speedup vs baseline: 1.2146x; 1.1184x over previous
//
#include <hip/hip_runtime.h>
#include <stdint.h>

typedef _Float16 f16;
typedef __attribute__((ext_vector_type(8))) _Float16 f16x8;
typedef __attribute__((ext_vector_type(4))) float f32x4;
typedef __attribute__((ext_vector_type(2))) unsigned int u32x2;
typedef __attribute__((ext_vector_type(4))) unsigned int u32x4;
typedef decltype(__builtin_amdgcn_cvt_pkrtz(0.f, 0.f)) h2_t;

#define S_LEN 2048
#define BATCH 8
#define D_IN  1024
#define DHALF 512

__device__ __forceinline__ unsigned lds_off(const void* p) {
  return (unsigned)(size_t)p;
}

// async global->LDS DMA, 16B per lane. LDS dest is wave-uniform base (+lane*16 by HW).
__device__ __forceinline__ void dma16(const void* g, void* lds_uniform) {
  __builtin_amdgcn_global_load_lds(
      (const __attribute__((address_space(1))) void*)g,
      (__attribute__((address_space(3))) void*)lds_uniform, 16, 0, 0);
}

// ---------------------------------------------------------------------------
// W f32 -> f16 preconvert (one-shot, ~3MB): out[z] = (f16)W[z], layout [n][k].
// ---------------------------------------------------------------------------
__global__ __launch_bounds__(256) void wcvt_kernel(
    const float* __restrict__ Wq, const float* __restrict__ Wk, const float* __restrict__ Wv,
    f16* __restrict__ out)
{
  const int z = blockIdx.y;
  const float* W = (z == 0) ? Wq : (z == 1) ? Wk : Wv;
  const int idx = (blockIdx.x * 256 + threadIdx.x) * 8;
  f32x4 a = *(const f32x4*)(W + idx);
  f32x4 b = *(const f32x4*)(W + idx + 4);
  union { h2_t h2[4]; f16x8 v; } u;
  u.h2[0] = __builtin_amdgcn_cvt_pkrtz(a.x, a.y);
  u.h2[1] = __builtin_amdgcn_cvt_pkrtz(a.z, a.w);
  u.h2[2] = __builtin_amdgcn_cvt_pkrtz(b.x, b.y);
  u.h2[3] = __builtin_amdgcn_cvt_pkrtz(b.z, b.w);
  *(f16x8*)(out + (size_t)z * (DHALF * D_IN) + idx) = u.v;
}

// ---------------------------------------------------------------------------
// Projection: out[s,b,e] = sum_d X[s,b,d] * W[e,d] + bias[e], stored fp16.
// Tile 128x128x32, 4 waves, 64x64/wave. Staging via global_load_lds DMA:
//   A staged as f32 (16KB/buf), pre-swizzled source byte ^= (row&7)<<4
//   B staged as f16 (8KB/buf, from preconverted Wf16), byte ^= ((row>>1)&3)<<4
// A-fragments: 2x ds_read_b128 f32 + 4 cvt_pkrtz -> f16x8 (VALU overlaps MFMA).
// One barrier per K-step; DMA(t+1) issued before compute(t) (m97 schedule).
// ---------------------------------------------------------------------------
__global__ __launch_bounds__(256, 3) void proj_kernel(
    const float* __restrict__ Xq, const float* __restrict__ Xk, const float* __restrict__ Xv,
    const f16* __restrict__ Wf16,
    const float* __restrict__ bq, const float* __restrict__ bk, const float* __restrict__ bv,
    f16* __restrict__ oq, f16* __restrict__ ok, f16* __restrict__ ov)
{
  const int z = blockIdx.z;
  const float* X    = (z == 0) ? Xq : (z == 1) ? Xk : Xv;
  const f16*   W    = Wf16 + (size_t)z * (DHALF * D_IN);
  const float* bias = (z == 0) ? bq : (z == 1) ? bk : bv;
  f16* out          = (z == 0) ? oq : (z == 1) ? ok : ov;

  const int m0 = blockIdx.x * 128;
  const int n0 = blockIdx.y * 128;
  const int tid = threadIdx.x;
  const int lane = tid & 63;
  const int wave = tid >> 6;
  const int wr = wave >> 1, wc = wave & 1;
  const int g = lane >> 4, rl = lane & 15;

  __shared__ float As[2][4096];   // [128 rows][32 k f32] linear, source-swizzled
  __shared__ f16   Bs[2][4096];   // [128 rows][32 k f16] linear, source-swizzled

  f32x4 acc[4][4];
#pragma unroll
  for (int i = 0; i < 4; i++)
#pragma unroll
    for (int j = 0; j < 4; j++) acc[i][j] = (f32x4){0.f, 0.f, 0.f, 0.f};

  // ---- DMA source/dest precompute ----
  // A: wave w stages LDS bytes [w*4096, (w+1)*4096): 4 instrs of 1KB.
  //    tile-local L = w*4096 + i*1024 + lane*16; row = L>>7;
  //    logical col byte = (L ^ ((row&7)<<4)) & 127
  const char* gaA[4];
  unsigned    ldA[4];
#pragma unroll
  for (int i = 0; i < 4; i++) {
    unsigned L   = wave * 4096 + i * 1024 + lane * 16;
    unsigned row = L >> 7;
    unsigned col = (L ^ ((row & 7) << 4)) & 127;
    gaA[i] = (const char*)X + (size_t)(m0 + row) * (D_IN * 4) + col;
    ldA[i] = wave * 4096 + i * 1024;   // uniform LDS byte offset within buffer
  }
  // B: wave w stages LDS bytes [w*2048, (w+1)*2048): 2 instrs.
  //    L = w*2048 + i*1024 + lane*16; row = L>>6; col = (L ^ (((row>>1)&3)<<4)) & 63
  const char* gaB[2];
  unsigned    ldB[2];
#pragma unroll
  for (int i = 0; i < 2; i++) {
    unsigned L   = wave * 2048 + i * 1024 + lane * 16;
    unsigned row = L >> 6;
    unsigned col = (L ^ (((row >> 1) & 3) << 4)) & 63;
    gaB[i] = (const char*)W + (size_t)(n0 + row) * (D_IN * 2) + col;
    ldB[i] = wave * 2048 + i * 1024;
  }

#define ISSUE(BUF, KSTEP) {                                                   \
  _Pragma("unroll")                                                           \
  for (int i = 0; i < 4; i++)                                                 \
    dma16(gaA[i] + (KSTEP) * 128, (char*)&As[BUF][0] + ldA[i]);               \
  _Pragma("unroll")                                                           \
  for (int i = 0; i < 2; i++)                                                 \
    dma16(gaB[i] + (KSTEP) * 64,  (char*)&Bs[BUF][0] + ldB[i]); }

#define PCOMPUTE(BUF) {                                                       \
  f16x8 bf[4];                                                                \
  _Pragma("unroll")                                                           \
  for (int j = 0; j < 4; j++) {                                               \
    unsigned row = wc * 64 + j * 16 + rl;                                     \
    unsigned off = row * 64 + ((g * 16) ^ (((rl >> 1) & 3) << 4));            \
    bf[j] = *(const f16x8*)((const char*)&Bs[BUF][0] + off);                  \
  }                                                                           \
  f16x8 af[4];                                                                \
  _Pragma("unroll")                                                           \
  for (int i = 0; i < 4; i++) {                                               \
    unsigned row = wr * 64 + i * 16 + rl;                                     \
    unsigned off = row * 128 + ((g * 32) ^ ((rl & 7) << 4));                  \
    f32x4 lo = *(const f32x4*)((const char*)&As[BUF][0] + off);               \
    f32x4 hi = *(const f32x4*)((const char*)&As[BUF][0] + (off ^ 16));        \
    union { h2_t h2[4]; f16x8 v; } u;                                         \
    u.h2[0] = __builtin_amdgcn_cvt_pkrtz(lo.x, lo.y);                         \
    u.h2[1] = __builtin_amdgcn_cvt_pkrtz(lo.z, lo.w);                         \
    u.h2[2] = __builtin_amdgcn_cvt_pkrtz(hi.x, hi.y);                         \
    u.h2[3] = __builtin_amdgcn_cvt_pkrtz(hi.z, hi.w);                         \
    af[i] = u.v;                                                              \
  }                                                                           \
  _Pragma("unroll")                                                           \
  for (int i = 0; i < 4; i++)                                                 \
    _Pragma("unroll")                                                         \
    for (int j = 0; j < 4; j++)                                               \
      acc[i][j] = __builtin_amdgcn_mfma_f32_16x16x32_f16(af[i], bf[j], acc[i][j], 0, 0, 0); }

  // prologue: stage step 0
  ISSUE(0, 0);
  __syncthreads();                 // vmcnt(0) drain -> buf0 ready

  // 32 K-steps; DMA(t+1) issued before compute(t); barrier drains DMA
  for (int k = 0; k < 31; ++k) {
    ISSUE((k + 1) & 1, k + 1);
    PCOMPUTE(k & 1);
    __syncthreads();
  }
  PCOMPUTE(1);                     // step 31 (31&1 == 1)
#undef ISSUE
#undef PCOMPUTE

  // epilogue: + bias, cast fp16; C/D layout: col = lane&15, row = (lane>>4)*4 + r
#pragma unroll
  for (int i = 0; i < 4; i++) {
    const int row = m0 + wr * 64 + i * 16 + g * 4;
#pragma unroll
    for (int j = 0; j < 4; j++) {
      const int col = n0 + wc * 64 + j * 16 + rl;
      const float bb = bias[col];
#pragma unroll
      for (int r = 0; r < 4; r++)
        out[(size_t)(row + r) * DHALF + col] = (f16)(acc[i][j][r] + bb);
    }
  }
}

// ---------------------------------------------------------------------------
// Batched GEMM-TN: C[b] = A[b] (M x K, K-contig) * B[b] (K x N, N-contig).
// Template MI = M-fragments per wave (4 -> BM=128, 2 -> BM=64).
// B transpose-staged into [4k][16n] subtiles, phys order {0,2,4,6,1,3,5,7},
// read via ds_read_b64_tr_b16 (+offset:512).
// EPI=0: apply attn mask, store f32 logits.  EPI=1: store f32 to out.
// ---------------------------------------------------------------------------
template <int EPI, int MI>
__global__ __launch_bounds__(256, 3) void gemm_tn_kernel(
    const f16* __restrict__ A, long batchA, int lda,
    const f16* __restrict__ Bm, long batchB, int ldb,
    int Ksize,
    const int* __restrict__ mask,
    float* __restrict__ out, long batchOut, int ldo)
{
  constexpr int BM = MI * 32;            // block M-tile
  const int bz = blockIdx.z;
  const int n0 = blockIdx.x * 128;
  const int m0 = blockIdx.y * BM;
  const f16* Ab = A + (size_t)bz * batchA;
  const f16* Bb = Bm + (size_t)bz * batchB;

  const int tid = threadIdx.x, lane = tid & 63, wave = tid >> 6;
  const int wr = wave >> 1, wc = wave & 1;
  const int g = lane >> 4, rl = lane & 15;

  __shared__ f16 As[2][BM * 40];         // padded stride 40
  __shared__ f16 Bs[2][32 * 128];        // [n_blk(8)][phys(8)] blocks of [4][16]

  f32x4 acc[MI][4];
#pragma unroll
  for (int i = 0; i < MI; i++)
#pragma unroll
    for (int j = 0; j < 4; j++) acc[i][j] = (f32x4){0.f, 0.f, 0.f, 0.f};

  // A staging: BM*32 f16 by 256 threads
  const int arow = (MI == 4) ? (tid >> 1) : (tid >> 2);
  const int ah   = (MI == 4) ? ((tid & 1) * 16) : ((tid & 3) * 8);
  const int brow = tid >> 3;             // k-row 0..31
  const int bcol = (tid & 7) * 16;       // n offset
  const int sblk = brow >> 2;
  const int phys = ((sblk & 1) << 2) | (sblk >> 1);
  const int bwoff = ((tid & 7) * 8 + phys) * 128 + (brow & 3) * 32;  // bytes
  const f16* gA = Ab + (size_t)(m0 + arow) * lda + ah;
  const f16* gB = Bb + (size_t)brow * ldb + n0 + bcol;

  const unsigned bs_base = lds_off(&Bs[0][0]);

  f16x8 va0, va1, vb0, vb1;

#define GLOAD(K0)                                                       \
  va0 = *(const f16x8*)(gA + (K0));                                     \
  if (MI == 4) va1 = *(const f16x8*)(gA + (K0) + 8);                    \
  { const f16* gb = gB + (size_t)(K0) * ldb;                            \
    vb0 = *(const f16x8*)(gb);                                          \
    vb1 = *(const f16x8*)(gb + 8); }

#define GWRITE(BUF) {                                                   \
  *(f16x8*)&As[BUF][arow * 40 + ah] = va0;                              \
  if (MI == 4) *(f16x8*)&As[BUF][arow * 40 + ah + 8] = va1;             \
  char* wb = (char*)&Bs[BUF][0] + bwoff;                                \
  *(f16x8*)wb        = vb0;                                             \
  *(f16x8*)(wb + 16) = vb1; }

  GLOAD(0);
  GWRITE(0);
  __syncthreads();

  int cur = 0;
#pragma unroll 2
  for (int k0 = 0; k0 < Ksize; k0 += 32) {
    const bool more = (k0 + 32 < Ksize);
    if (more) { GLOAD(k0 + 32); }

    f16x8 af[MI];
#pragma unroll
    for (int i = 0; i < MI; i++)
      af[i] = *(const f16x8*)&As[cur][(wr * (MI * 16) + i * 16 + rl) * 40 + g * 8];

    f16x8 bf[4];
#pragma unroll
    for (int j = 0; j < 4; j++) {
      unsigned addr = bs_base + (unsigned)cur * 8192u +
                      (unsigned)((wc * 4 + j) * 1024) + (unsigned)lane * 8u;
      u32x2 lo, hi;
      asm volatile("ds_read_b64_tr_b16 %0, %1" : "=v"(lo) : "v"(addr));
      asm volatile("ds_read_b64_tr_b16 %0, %1 offset:512" : "=v"(hi) : "v"(addr));
      union { u32x4 u; f16x8 h; } cc;
      cc.u = (u32x4){lo.x, lo.y, hi.x, hi.y};
      bf[j] = cc.h;
    }
    // rule 18: fence tr-read results before register-only MFMA consumers
    asm volatile("s_waitcnt lgkmcnt(0)" ::: "memory");
    __builtin_amdgcn_sched_barrier(0);

#pragma unroll
    for (int i = 0; i < MI; i++)
#pragma unroll
      for (int j = 0; j < 4; j++)
        acc[i][j] = __builtin_amdgcn_mfma_f32_16x16x32_f16(af[i], bf[j], acc[i][j], 0, 0, 0);

    if (more) {
      GWRITE(cur ^ 1);
      __syncthreads();
      cur ^= 1;
    }
  }
#undef GLOAD
#undef GWRITE

  float* ob = out + (size_t)bz * batchOut;
#pragma unroll
  for (int i = 0; i < MI; i++) {
    const int row = m0 + wr * (MI * 16) + i * 16 + g * 4;
#pragma unroll
    for (int j = 0; j < 4; j++) {
      const int col = n0 + wc * 64 + j * 16 + rl;
#pragma unroll
      for (int r = 0; r < 4; r++) {
        float val = acc[i][j][r];
        if (EPI == 0) {
          if (mask[(row + r) * DHALF + col] != 0) val = -1e30f;
        }
        ob[(size_t)(row + r) * ldo + col] = val;
      }
    }
  }
}

// ---------------------------------------------------------------------------
// Row softmax over e (512) for 4096 rows; one wave per row; fp16 output.
// ---------------------------------------------------------------------------
__global__ __launch_bounds__(256) void softmax_kernel(
    const float* __restrict__ logits, f16* __restrict__ P)
{
  const int row  = blockIdx.x * 4 + (threadIdx.x >> 6);
  const int lane = threadIdx.x & 63;
  const float* rp = logits + (size_t)row * DHALF + lane * 8;
  f32x4 x0 = *(const f32x4*)rp;
  f32x4 x1 = *(const f32x4*)(rp + 4);

  float m = fmaxf(fmaxf(fmaxf(x0.x, x0.y), fmaxf(x0.z, x0.w)),
                  fmaxf(fmaxf(x1.x, x1.y), fmaxf(x1.z, x1.w)));
#pragma unroll
  for (int off = 32; off > 0; off >>= 1) m = fmaxf(m, __shfl_xor(m, off, 64));

  float e0 = __expf(x0.x - m), e1 = __expf(x0.y - m);
  float e2 = __expf(x0.z - m), e3 = __expf(x0.w - m);
  float e4 = __expf(x1.x - m), e5 = __expf(x1.y - m);
  float e6 = __expf(x1.z - m), e7 = __expf(x1.w - m);
  float s = ((e0 + e1) + (e2 + e3)) + ((e4 + e5) + (e6 + e7));
#pragma unroll
  for (int off = 32; off > 0; off >>= 1) s += __shfl_xor(s, off, 64);
  const float inv = 1.0f / s;

  union { h2_t h2[4]; f16x8 v; } o;
  o.h2[0] = __builtin_amdgcn_cvt_pkrtz(e0 * inv, e1 * inv);
  o.h2[1] = __builtin_amdgcn_cvt_pkrtz(e2 * inv, e3 * inv);
  o.h2[2] = __builtin_amdgcn_cvt_pkrtz(e4 * inv, e5 * inv);
  o.h2[3] = __builtin_amdgcn_cvt_pkrtz(e6 * inv, e7 * inv);
  *(f16x8*)(P + (size_t)row * DHALF + lane * 8) = o.v;
}

// ---------------------------------------------------------------------------
extern "C" void kernel_launch(void* const* d_in, const int* in_sizes, int n_in,
                              void* d_out, int out_size, void* d_ws, size_t ws_size,
                              hipStream_t stream) {
  const float* q    = (const float*)d_in[0];
  const float* k    = (const float*)d_in[1];
  const float* v    = (const float*)d_in[2];
  const int*   mask = (const int*)d_in[3];
  const float* Wq   = (const float*)d_in[4];
  const float* bq   = (const float*)d_in[5];
  const float* Wk   = (const float*)d_in[6];
  const float* bk   = (const float*)d_in[7];
  const float* Wv   = (const float*)d_in[8];
  const float* bv   = (const float*)d_in[9];

  char* ws = (char*)d_ws;
  f16*   qt     = (f16*)(ws);                                  // 16 MB
  f16*   kt     = (f16*)(ws + 16777216);                       // 16 MB
  f16*   vt     = (f16*)(ws + 2 * 16777216);                   // 16 MB
  float* logits = (float*)(ws + 3 * 16777216);                 // 8 MB
  f16*   P      = (f16*)(ws + 3 * 16777216 + 8388608);         // 4 MB
  // Wf16 (3 MB) overlaps the logits region: consumed by proj before QK writes logits
  f16*   Wf16   = (f16*)(ws + 3 * 16777216);

  // 0) preconvert weights to fp16
  wcvt_kernel<<<dim3(256, 3), 256, 0, stream>>>(Wq, Wk, Wv, Wf16);
  // 1) fused q/k/v projections -> fp16 (S,B,DH) flat
  proj_kernel<<<dim3(128, 4, 3), 256, 0, stream>>>(q, k, v, Wf16, bq, bk, bv,
                                                   qt, kt, vt);
  // 2) logits[b,d,e] = sum_s q_[b,d,s] k_[b,s,e]  (+mask -> -1e30), BM=64 -> 256 blocks
  gemm_tn_kernel<0, 2><<<dim3(4, 8, 8), 256, 0, stream>>>(
      qt, 1048576L, 2048, kt, 1048576L, 512, 2048, mask, logits, 262144L, 512);
  // 3) P = softmax(logits) over e, fp16
  softmax_kernel<<<dim3(1024), 256, 0, stream>>>(logits, P);
  // 4) out[b,d,s] = sum_e P[b,d,e] v_[b,e,s]  -> f32 d_out, BM=128 -> 512 blocks
  gemm_tn_kernel<1, 4><<<dim3(16, 4, 8), 256, 0, stream>>>(
      P, 262144L, 512, vt, 1048576L, 2048, 512, nullptr, (float*)d_out, 1048576L, 2048);
}